// Round 1
// 713.242 us; speedup vs baseline: 1.1484x; 1.1484x over previous
//
#include <hip/hip_runtime.h>
#include <stdint.h>

// BinaryLinear: out[M,N] = x[M,K] @ sign(W[N,K])^T + bias[N]
// M=16384, N=4096, K=4096.
// R3: 256x256 8-phase counted-vmcnt i8 GEMM (T2+T3+T4+T5 port of the
// verified bf16 template; BK=128 i8 == 128B rows == bf16 BK=64 geometry).
// LDS swizzle: byte ^= ((row&7)<<4)  (proved conflict-free for columnar
// ds_read_b128 of 128B rows; applied to BOTH global-source and ds_read).

using i32x4 = __attribute__((ext_vector_type(4))) int;

#define QSCALE     (6.2f / 127.0f)     // dequant scale
#define QINVSCALE  (127.0f / 6.2f)     // quant scale

__device__ __forceinline__ void async_copy16(const void* g, void* l) {
    __builtin_amdgcn_global_load_lds(
        (const __attribute__((address_space(1))) void*)g,
        (__attribute__((address_space(3))) void*)l, 16, 0, 0);
}

// ---- conversion kernels -------------------------------------------------

__device__ __forceinline__ uint32_t quant4(float4 v) {
    int q0 = __float2int_rn(v.x * QINVSCALE);
    int q1 = __float2int_rn(v.y * QINVSCALE);
    int q2 = __float2int_rn(v.z * QINVSCALE);
    int q3 = __float2int_rn(v.w * QINVSCALE);
    q0 = max(-127, min(127, q0));
    q1 = max(-127, min(127, q1));
    q2 = max(-127, min(127, q2));
    q3 = max(-127, min(127, q3));
    return (uint32_t)(q0 & 0xFF) | ((uint32_t)(q1 & 0xFF) << 8) |
           ((uint32_t)(q2 & 0xFF) << 16) | ((uint32_t)(q3 & 0xFF) << 24);
}

__global__ void cvt_x_i8(const float4* __restrict__ in,
                         uint32_t* __restrict__ out, int n4) {
    int i = blockIdx.x * blockDim.x + threadIdx.x;
    int stride = gridDim.x * blockDim.x;
    for (; i < n4; i += stride) out[i] = quant4(in[i]);
}

__global__ void cvt_w_sign_i8(const float4* __restrict__ in,
                              uint32_t* __restrict__ out, int n4) {
    int i = blockIdx.x * blockDim.x + threadIdx.x;
    int stride = gridDim.x * blockDim.x;
    for (; i < n4; i += stride) {
        float4 v = in[i];
        uint32_t b0 = (v.x >= 0.0f) ? 0x01u : 0xFFu;
        uint32_t b1 = (v.y >= 0.0f) ? 0x01u : 0xFFu;
        uint32_t b2 = (v.z >= 0.0f) ? 0x01u : 0xFFu;
        uint32_t b3 = (v.w >= 0.0f) ? 0x01u : 0xFFu;
        out[i] = b0 | (b1 << 8) | (b2 << 16) | (b3 << 24);
    }
}

// ---- 256x256 8-phase GEMM ----------------------------------------------
// 8 waves (2M x 4N), per-wave output 128x64, BK=128 i8.
// LDS: 2 buffers x (A 256x128B + B 256x128B) = 128 KiB.
// Per phase: ds_read subtile || stage 1 half-tile -> barrier -> lgkmcnt(0)
// -> setprio(1) 16x MFMA setprio(0) -> [vmcnt(4) @ ph4/ph8] -> barrier.

#define BM 256
#define BN 256
#define BK 128

#define AOFF(d, h) ((d) * 65536 + (h) * 16384)
#define BOFF(d, h) ((d) * 65536 + 32768 + (h) * 16384)
#define SWZ(off)   ((off) ^ ((((off) >> 7) & 7) << 4))

#define LDA(d, row, colb) \
    (*(const i32x4*)(smem + (d) * 65536 + SWZ((row) * 128 + (colb))))
#define LDB(d, row, colb) \
    (*(const i32x4*)(smem + (d) * 65536 + 32768 + SWZ((row) * 128 + (colb))))

#define READ_A(d, mq)                                                        \
    _Pragma("unroll") for (int i = 0; i < 4; ++i) {                          \
        _Pragma("unroll") for (int ks = 0; ks < 2; ++ks) {                   \
            a[i][ks] = LDA(d, wm * 128 + (mq) * 64 + i * 16 + r16,           \
                           ks * 64 + quad * 16);                             \
        }                                                                    \
    }

#define READ_B(d, nq, bb)                                                    \
    _Pragma("unroll") for (int j = 0; j < 2; ++j) {                          \
        _Pragma("unroll") for (int ks = 0; ks < 2; ++ks) {                   \
            bb[j][ks] = LDB(d, wn * 64 + (nq) * 32 + j * 16 + r16,           \
                            ks * 64 + quad * 16);                            \
        }                                                                    \
    }

#define MFMA_Q(mq, nq, bb)                                                   \
    __builtin_amdgcn_s_setprio(1);                                           \
    _Pragma("unroll") for (int ks = 0; ks < 2; ++ks) {                       \
        _Pragma("unroll") for (int i = 0; i < 4; ++i) {                      \
            _Pragma("unroll") for (int j = 0; j < 2; ++j) {                  \
                acc[(mq) * 4 + i][(nq) * 2 + j] =                            \
                    __builtin_amdgcn_mfma_i32_16x16x64_i8(                   \
                        a[i][ks], bb[j][ks],                                 \
                        acc[(mq) * 4 + i][(nq) * 2 + j], 0, 0, 0);           \
            }                                                                \
        }                                                                    \
    }                                                                        \
    __builtin_amdgcn_s_setprio(0);

#define BAR()        __builtin_amdgcn_s_barrier()
#define WAIT_LGKM0() asm volatile("s_waitcnt lgkmcnt(0)" ::: "memory")
#define WAIT_VM(n)   asm volatile("s_waitcnt vmcnt(" #n ")" ::: "memory")

__global__ __launch_bounds__(512, 2)
void gemm_bt_i8_8ph(const int8_t* __restrict__ A,   // [M,K]
                    const int8_t* __restrict__ B,   // [N,K]
                    const float*  __restrict__ bias,
                    float* __restrict__ C,
                    int M, int N, int K) {
    __shared__ __align__(16) int8_t smem[131072];   // 128 KiB

    // XCD-aware bijective swizzle (nwg = 1024, divisible by 8)
    const int nwg  = gridDim.x;
    const int cpx  = nwg >> 3;
    const int bid  = blockIdx.x;
    const int wgid = (bid & 7) * cpx + (bid >> 3);

    const int ntn = N / BN;                   // 16
    const int m0  = (wgid / ntn) * BM;
    const int n0  = (wgid % ntn) * BN;

    const int tid  = threadIdx.x;
    const int wave = tid >> 6;     // 0..7
    const int lane = tid & 63;
    const int wm   = wave >> 2;    // 0..1
    const int wn   = wave & 3;     // 0..3
    const int quad = lane >> 4;    // 0..3
    const int r16  = lane & 15;

    i32x4 acc[8][4] = {};
    i32x4 a[4][2], b0[2][2], b1[2][2];

    const int NT = K / BK;                    // 32

    const int8_t* Abase = A + (size_t)m0 * K;
    const int8_t* Bbase = B + (size_t)n0 * K;
#define GA(kt, h) (Abase + (size_t)((h) * 128) * K + (kt) * BK)
#define GB(kt, h) (Bbase + (size_t)((h) * 128) * K + (kt) * BK)

    // stage one half-tile (128 rows x 128B): linear LDS dest, pre-swizzled
    // global source (rule #21: both-sides-or-neither).
    auto STAGE = [&](const int8_t* grow0, int lds_off) {
#pragma unroll
        for (int c = 0; c < 2; ++c) {
            const int off = (tid << 4) + (c << 13);   // dest offset in half
            const int src = SWZ(off);                 // permuted source
            async_copy16(grow0 + (size_t)(src >> 7) * K + (src & 127),
                         smem + lds_off + (wave << 10) + (c << 13));
        }
    };

    // ---- prologue: tile0 (all 4 halves) + tile1 B halves; vmcnt(4) -----
    STAGE(GA(0, 0), AOFF(0, 0));
    STAGE(GA(0, 1), AOFF(0, 1));
    STAGE(GB(0, 0), BOFF(0, 0));
    STAGE(GB(0, 1), BOFF(0, 1));
    STAGE(GB(1, 0), BOFF(1, 0));
    STAGE(GB(1, 1), BOFF(1, 1));
    WAIT_VM(4);                    // tile0 landed; tile1 B halves in flight
    BAR();

    // ---- main loop: 2 K-tiles / iteration, 8 phases --------------------
    for (int t = 0; t < NT; t += 2) {
        const int t1 = t + 1;
        const int t2 = (t + 2 < NT) ? t + 2 : NT - 1;   // tail clamp
        const int t3 = (t + 3 < NT) ? t + 3 : NT - 1;

        // phase 1: Q(0,0) buf0 | stage A0(t+1)->buf1
        READ_A(0, 0)
        READ_B(0, 0, b0)
        STAGE(GA(t1, 0), AOFF(1, 0));
        BAR(); WAIT_LGKM0();
        MFMA_Q(0, 0, b0)
        BAR();

        // phase 2: Q(0,1) buf0 | stage A1(t+1)->buf1
        READ_B(0, 1, b1)
        STAGE(GA(t1, 1), AOFF(1, 1));
        BAR(); WAIT_LGKM0();
        MFMA_Q(0, 1, b1)
        BAR();

        // phase 3: Q(1,0) buf0 | stage B0(t+2)->buf0 (B reads drained ph2)
        READ_A(0, 1)
        STAGE(GB(t2, 0), BOFF(0, 0));
        BAR(); WAIT_LGKM0();
        MFMA_Q(1, 0, b0)
        BAR();

        // phase 4: Q(1,1) buf0 | stage B1(t+2)->buf0 | vmcnt(4): t+1 landed
        STAGE(GB(t2, 1), BOFF(0, 1));
        BAR(); WAIT_LGKM0();
        MFMA_Q(1, 1, b1)
        WAIT_VM(4);
        BAR();

        // phase 5: Q(0,0) buf1 | stage A0(t+2)->buf0 (A reads drained ph3)
        READ_A(1, 0)
        READ_B(1, 0, b0)
        STAGE(GA(t2, 0), AOFF(0, 0));
        BAR(); WAIT_LGKM0();
        MFMA_Q(0, 0, b0)
        BAR();

        // phase 6: Q(0,1) buf1 | stage A1(t+2)->buf0
        READ_B(1, 1, b1)
        STAGE(GA(t2, 1), AOFF(0, 1));
        BAR(); WAIT_LGKM0();
        MFMA_Q(0, 1, b1)
        BAR();

        // phase 7: Q(1,0) buf1 | stage B0(t+3)->buf1
        READ_A(1, 1)
        STAGE(GB(t3, 0), BOFF(1, 0));
        BAR(); WAIT_LGKM0();
        MFMA_Q(1, 0, b0)
        BAR();

        // phase 8: Q(1,1) buf1 | stage B1(t+3)->buf1 | vmcnt(4): t+2 landed
        STAGE(GB(t3, 1), BOFF(1, 1));
        BAR(); WAIT_LGKM0();
        MFMA_Q(1, 1, b1)
        WAIT_VM(4);
        BAR();
    }

    WAIT_VM(0);   // drain tail stages before LDS dealloc at endpgm

    // ---- epilogue: C/D layout col=lane&15, row=quad*4+reg ---------------
#pragma unroll
    for (int jj = 0; jj < 4; ++jj) {
        const int col = n0 + wn * 64 + jj * 16 + r16;
        const float bv = bias[col];
#pragma unroll
        for (int ii = 0; ii < 8; ++ii) {
            const int rowbase = m0 + wm * 128 + ii * 16 + quad * 4;
#pragma unroll
            for (int reg = 0; reg < 4; ++reg) {
                C[(size_t)(rowbase + reg) * N + col] =
                    (float)acc[ii][jj][reg] * QSCALE + bv;
            }
        }
    }
}

// ---- fallback (ws too small): naive fp32 --------------------------------

__global__ void gemm_naive(const float* __restrict__ x,
                           const float* __restrict__ w,
                           const float* __restrict__ bias,
                           float* __restrict__ out, int M, int N, int K) {
    int idx = blockIdx.x * blockDim.x + threadIdx.x;
    if (idx >= M * N) return;
    int m = idx / N, n = idx % N;
    const float4* xr = (const float4*)(x + (size_t)m * K);
    const float4* wr = (const float4*)(w + (size_t)n * K);
    float s = 0.f;
    for (int k = 0; k < K / 4; ++k) {
        float4 a = xr[k], b = wr[k];
        s += (b.x >= 0.f ? a.x : -a.x);
        s += (b.y >= 0.f ? a.y : -a.y);
        s += (b.z >= 0.f ? a.z : -a.z);
        s += (b.w >= 0.f ? a.w : -a.w);
    }
    out[idx] = s + bias[n];
}

extern "C" void kernel_launch(void* const* d_in, const int* in_sizes, int n_in,
                              void* d_out, int out_size, void* d_ws, size_t ws_size,
                              hipStream_t stream) {
    const float* x    = (const float*)d_in[0];  // [8,2048,4096]
    const float* w    = (const float*)d_in[1];  // [4096,4096]
    const float* bias = (const float*)d_in[2];  // [4096]
    float* out = (float*)d_out;

    const int M = 16384, N = 4096, K = 4096;
    const size_t xb_bytes = (size_t)M * K;      // 67 MB int8
    const size_t wb_bytes = (size_t)N * K;      // 17 MB int8

    if (ws_size >= xb_bytes + wb_bytes) {
        int8_t* xb = (int8_t*)d_ws;
        int8_t* wb = (int8_t*)d_ws + xb_bytes;

        cvt_x_i8<<<8192, 256, 0, stream>>>((const float4*)x, (uint32_t*)xb,
                                           (M * K) / 4);
        cvt_w_sign_i8<<<2048, 256, 0, stream>>>((const float4*)w, (uint32_t*)wb,
                                                (N * K) / 4);
        gemm_bt_i8_8ph<<<(M / BM) * (N / BN), 512, 0, stream>>>(
            xb, wb, bias, out, M, N, K);
    } else {
        gemm_naive<<<(M * N + 255) / 256, 256, 0, stream>>>(x, w, bias, out,
                                                            M, N, K);
    }
}